// Round 3
// baseline (3374.486 us; speedup 1.0000x reference)
//
#include <hip/hip_runtime.h>

// Problem constants: B=8, S=4096, D=2048
#define N_TOK   32768L
#define DMODEL  2048L
#define E1      6144L
#define ROT     1024
#define SMASK   4095

typedef __attribute__((ext_vector_type(8))) _Float16 half8;
typedef __attribute__((ext_vector_type(4))) _Float16 half4;
typedef __attribute__((ext_vector_type(4))) float    floatx4;
typedef __attribute__((ext_vector_type(4))) float    float4v;

// async global->LDS, 16B/lane; LDS dest = wave-uniform base + lane*16.
__device__ inline void gld16(const void* g, void* l) {
  __builtin_amdgcn_global_load_lds(
      (const __attribute__((address_space(1))) unsigned int*)g,
      (__attribute__((address_space(3))) unsigned int*)l,
      16, 0, 0);
}

// ---------------------------------------------------------------- converts
__global__ __launch_bounds__(256) void k_f2h(const float* __restrict__ in,
                                             _Float16* __restrict__ out,
                                             long nElem) {
  long i = ((long)blockIdx.x * 256 + threadIdx.x) * 4;
  if (i + 3 < nElem) {
    float4v v = *(const float4v*)(in + i);
    half4 o;
    o[0] = (_Float16)v[0]; o[1] = (_Float16)v[1];
    o[2] = (_Float16)v[2]; o[3] = (_Float16)v[3];
    *(half4*)(out + i) = o;
  }
}

__global__ __launch_bounds__(256) void k_zero(float* __restrict__ p, int n) {
  int i = blockIdx.x * 256 + threadIdx.x;
  if (i < n) p[i] = 0.f;
}

// ---------------------------------------------------------------- rope table
__global__ __launch_bounds__(256) void k_tab(float2* __restrict__ tab) {
  int i = blockIdx.x * 256 + threadIdx.x;   // [0, 4096*512)
  int s = i >> 9, j = i & 511;
  float invf = (float)pow(10000.0, -(double)j / 512.0);
  float ang  = (float)s * invf;
  double sd, cd; sincos((double)ang, &sd, &cd);
  float2 o; o.x = (float)cd; o.y = (float)sd;
  tab[i] = o;
}

// ---------------------------------------------------------------- GEMM 256x256, 8-phase
// C[m][e] = sum_d A[m][d]*B[e][d] (+bias) (+X residual, fp32 out)
//
// 512 thr = 8 waves (2M x 4N). Per-wave output 128x64: two 64-row A-halves x
// two 32-col B-halves -> 4 quadrants, one per phase, K=64 per phase.
// Quadrant order (0,0)->(0,1)->(1,1)->(1,0): af (A-half frags, 8 reads)
// reused across phase pairs; bf (B-half frags, 4 reads) reloaded per phase
// (B0 re-read at P4). Reads/phase = {12,4,8,4} = 28/K-tile.
//
// LDS 128 KiB: As/Bs[buf(2)][half(2)][128 rows][8 chunks of 16B], bank
// swizzle chunk' = chunk ^ (row&7) applied by inverse-permuting the GLOBAL
// source address (global_load_lds writes linearly). Measured 0 conflicts.
//
// NO explicit lgkmcnt(0)/sched_barrier before the MFMA cluster: the ds_reads
// are compiler-visible C++ loads, so the compiler emits fine-grained
// lgkmcnt(N) per frag use -- early MFMAs overlap late read latency, and
// register-only MFMAs may sink into the next phase's read window (both are
// the LDS-pipe/matrix-pipe overlap this schedule needs; forcing a full drain
// + order pin was the m141-style regression).
//
// Stage cadence: exactly 1 half-tile per phase, vmcnt(6) at P4/P8 only:
//  P1: B0(T+1)->b1  P2: A0(T+2)->b0  P3: B1(T+2)->b0  P4: A1(T+2)->b0 +vm6
//  P5: B0(T+2)->b0  P6: A0(T+3)->b1  P7: B1(T+3)->b1  P8: A1(T+3)->b1 +vm6
// vm6@P4 retires {prev P6,P7,P8, P1} = tile T+1 complete before P5; leaves
// P2,P3,P4 in flight (3-phase lead). vm6@P8 retires {P2..P5} = tile T+2
// complete before next P1. Every stage targets a slot whose last ds_read
// closed >=1 barrier earlier. Last iteration peeled, vmcnt(0) at its P4.

#define MM(qm, qn) do { \
  _Pragma("unroll") for (int m4 = 0; m4 < 4; m4++) \
  _Pragma("unroll") for (int n2 = 0; n2 < 2; n2++) { \
    acc[(qm)*4+m4][(qn)*2+n2] = __builtin_amdgcn_mfma_f32_16x16x32_f16( \
        af[m4][0], bf[n2][0], acc[(qm)*4+m4][(qn)*2+n2], 0, 0, 0); \
    acc[(qm)*4+m4][(qn)*2+n2] = __builtin_amdgcn_mfma_f32_16x16x32_f16( \
        af[m4][1], bf[n2][1], acc[(qm)*4+m4][(qn)*2+n2], 0, 0, 0); \
  } } while (0)

#define LD_A(buf, qm) do { \
  const _Float16* pA_ = &As[(buf)*16384 + (qm)*8192 + baseA]; \
  _Pragma("unroll") for (int m4 = 0; m4 < 4; m4++) { \
    af[m4][0] = *(const half8*)(pA_ + m4*1024 + okA0); \
    af[m4][1] = *(const half8*)(pA_ + m4*1024 + okA1); \
  } } while (0)

#define LD_B(buf, qn) do { \
  const _Float16* pB_ = &Bs[(buf)*16384 + (qn)*8192 + baseB]; \
  _Pragma("unroll") for (int n2 = 0; n2 < 2; n2++) { \
    bf[n2][0] = *(const half8*)(pB_ + n2*1024 + okB0); \
    bf[n2][1] = *(const half8*)(pB_ + n2*1024 + okB1); \
  } } while (0)

#define STG_A(buf, h, kt) do { \
  const _Float16* gA_ = gA + (long)(h)*128*LDA + (long)(kt)*64; \
  gld16(gA_,          dA + (buf)*16384 + (h)*8192); \
  gld16(gA_ + 8*LDA,  dA + (buf)*16384 + (h)*8192 + 512); \
  } while (0)

#define STG_B(buf, h, kt) do { \
  const _Float16* gB_ = gB + (long)(h)*128*2048 + (long)(kt)*64; \
  gld16(gB_,          dB + (buf)*16384 + (h)*8192); \
  gld16(gB_ + 8*2048, dB + (buf)*16384 + (h)*8192 + 512); \
  } while (0)

#define VM6  asm volatile("s_waitcnt vmcnt(6)" ::: "memory")
#define VM0  asm volatile("s_waitcnt vmcnt(0)" ::: "memory")
#define NOP_ ((void)0)

#define PHASE(LDRD, STG, MMA_, WV) do { \
  LDRD; STG; \
  asm volatile("" ::: "memory"); \
  __builtin_amdgcn_s_barrier(); \
  asm volatile("" ::: "memory"); \
  __builtin_amdgcn_s_setprio(1); \
  MMA_; \
  __builtin_amdgcn_s_setprio(0); \
  WV; \
  asm volatile("" ::: "memory"); \
  __builtin_amdgcn_s_barrier(); \
  asm volatile("" ::: "memory"); \
  } while (0)

template <int EB, long LDA, long LDC, bool FP32OUT>
__global__ __launch_bounds__(512, 2) void k_gemm256(
    const _Float16* __restrict__ Ag, const _Float16* __restrict__ Bg,
    const float* __restrict__ bias, const float* __restrict__ Xres,
    void* __restrict__ Cout) {
  __shared__ _Float16 As[32768];   // 64 KiB
  __shared__ _Float16 Bs[32768];   // 64 KiB

  const int t    = threadIdx.x;
  const int w    = t >> 6;
  const int l    = t & 63;
  const int quad = l >> 4;
  const int ln   = l & 15;
  const int wr   = w >> 2;   // 0..1
  const int wc   = w & 3;    // 0..3

  // XCD-aware bijective remap (nwg%8==0), then e-major (A-panel L2 reuse).
  const int nwg = 128 * EB;
  const int bid = ((int)blockIdx.x & 7) * (nwg >> 3) + ((int)blockIdx.x >> 3);
  const int eb  = bid % EB;
  const int mb  = bid / EB;
  const long mRow0 = (long)mb * 256;
  const long eCol0 = (long)eb * 256;

  // staging per-thread geometry (inverse-swizzled source)
  const int stR = (w << 4) + (l >> 3);
  const int stC = ((l & 7) ^ (l >> 3)) << 3;
  const _Float16* gA = Ag + (mRow0 + stR) * LDA  + stC;
  const _Float16* gB = Bg + (eCol0 + stR) * 2048 + stC;
  _Float16* dA = &As[(w * 128 + l) * 8];
  _Float16* dB = &Bs[(w * 128 + l) * 8];

  // fragment-read geometry
  const int rA = (wr << 6) + ln;          // row within A-half
  const int rB = (wc << 5) + ln;          // row (=col of C) within B-half
  const int baseA = rA * 64;
  const int baseB = rB * 64;
  const int okA0 = ((quad    ) ^ (rA & 7)) << 3;  // kk=0 swizzled chunk
  const int okA1 = ((quad ^ 4) ^ (rA & 7)) << 3;  // kk=1
  const int okB0 = ((quad    ) ^ (rB & 7)) << 3;
  const int okB1 = ((quad ^ 4) ^ (rB & 7)) << 3;

  floatx4 acc[8][4];
#pragma unroll
  for (int i = 0; i < 8; i++)
#pragma unroll
    for (int j = 0; j < 4; j++) acc[i][j] = (floatx4){0.f, 0.f, 0.f, 0.f};
  half8 af[4][2], bf[2][2];

  // prologue: tile0 full (buf0) + A0,B1,A1 of tile1 (buf1). vmcnt(6) retires
  // tile0's 8 loads; tile1's 3 half-tiles stay in flight (P1 stages its B0).
  STG_A(0, 0, 0); STG_B(0, 0, 0); STG_B(0, 1, 0); STG_A(0, 1, 0);
  STG_A(1, 0, 1); STG_B(1, 1, 1); STG_A(1, 1, 1);
  VM6;
  asm volatile("" ::: "memory");
  __builtin_amdgcn_s_barrier();
  asm volatile("" ::: "memory");

#pragma unroll 1
  for (int it = 0; it < 15; ++it) {
    const int T = it * 2;
    PHASE({ LD_A(0,0); LD_B(0,0); }, STG_B(1,0,T+1), MM(0,0), NOP_);
    PHASE(LD_B(0,1),                 STG_A(0,0,T+2), MM(0,1), NOP_);
    PHASE(LD_A(0,1),                 STG_B(0,1,T+2), MM(1,1), NOP_);
    PHASE(LD_B(0,0),                 STG_A(0,1,T+2), MM(1,0), VM6);
    PHASE({ LD_A(1,0); LD_B(1,0); }, STG_B(0,0,T+2), MM(0,0), NOP_);
    PHASE(LD_B(1,1),                 STG_A(1,0,T+3), MM(0,1), NOP_);
    PHASE(LD_A(1,1),                 STG_B(1,1,T+3), MM(1,1), NOP_);
    PHASE(LD_B(1,0),                 STG_A(1,1,T+3), MM(1,0), VM6);
  }
  // peeled last iteration (T=30): tiles 32/33 don't exist; only tile 31's
  // B0 remains to stage (A0,B1,A1 staged by iter 14). vmcnt(0) at P4.
  PHASE({ LD_A(0,0); LD_B(0,0); }, STG_B(1,0,31), MM(0,0), NOP_);
  PHASE(LD_B(0,1),                 NOP_,          MM(0,1), NOP_);
  PHASE(LD_A(0,1),                 NOP_,          MM(1,1), NOP_);
  PHASE(LD_B(0,0),                 NOP_,          MM(1,0), VM0);
  PHASE({ LD_A(1,0); LD_B(1,0); }, NOP_,          MM(0,0), NOP_);
  PHASE(LD_B(1,1),                 NOP_,          MM(0,1), NOP_);
  PHASE(LD_A(1,1),                 NOP_,          MM(1,1), NOP_);
  PHASE(LD_B(1,0),                 NOP_,          MM(1,0), NOP_);

  // epilogue. C/D frag: col = lane&15, row = quad*4 + reg.
#pragma unroll
  for (int nt = 0; nt < 4; nt++) {
    const long e = eCol0 + ((nt >> 1) * 128 + (wc << 5) + ((nt & 1) << 4) + ln);
    const float bi = bias[e];
#pragma unroll
    for (int mt = 0; mt < 8; mt++) {
      const long m0 = mRow0 +
          ((mt >> 2) * 128 + (wr << 6) + ((mt & 3) << 4) + (quad << 2));
#pragma unroll
      for (int r = 0; r < 4; r++) {
        const long m = m0 + r;
        if constexpr (FP32OUT) {
          ((float*)Cout)[m * LDC + e] = acc[mt][nt][r] + bi + Xres[m * LDC + e];
        } else {
          ((_Float16*)Cout)[m * LDC + e] = (_Float16)(acc[mt][nt][r] + bi);
        }
      }
    }
  }
}

// ---------------------------------------------------------------- reduce A
// A[b][d] = sum_s rope(K)[b,s,d]/||rope(K)[b,s,:]|| * V[b,s,d]
// 2048 blocks (8/CU, full occupancy): latency-bound serial-row shape needs
// TLP, not fewer atomics (16M distinct-address fp32 atomics ~ negligible).
__global__ __launch_bounds__(256) void k_reduce_a(
    const _Float16* __restrict__ QKV, const float2* __restrict__ tab,
    float* __restrict__ A) {
  const int t  = threadIdx.x;
  const int w  = t >> 6;
  const int l  = t & 63;
  const int wg = blockIdx.x * 4 + w;      // 0..8191
  const long row0 = (long)wg * 4;         // 4 rows per wave, same b
  const int b  = (int)(row0 >> 12);
  const int d0 = l * 32;                  // lane covers 32 contiguous d

  float acc[32];
  for (int j = 0; j < 32; j++) acc[j] = 0.f;

  for (int i = 0; i < 4; i++) {
    const long n = row0 + i;
    const int  s = (int)(n & SMASK);
    const _Float16* Kr = QKV + n * E1 + DMODEL     + d0;
    const _Float16* Vr = QKV + n * E1 + 2 * DMODEL + d0;
    float kx[32];
    for (int c = 0; c < 4; c++) {
      half8 h = *(const half8*)(Kr + c * 8);
      for (int j = 0; j < 8; j++) kx[c * 8 + j] = (float)h[j];
    }
    if (d0 < ROT) {
      const float2* trow = tab + ((long)s << 9) + (d0 >> 1);
      for (int p = 0; p < 16; p++) {
        float2 cs2 = trow[p];
        float x0 = kx[2 * p], x1 = kx[2 * p + 1];
        kx[2 * p]     = x0 * cs2.x - x1 * cs2.y;
        kx[2 * p + 1] = x1 * cs2.x + x0 * cs2.y;
      }
    }
    float ss = 0.f;
    for (int j = 0; j < 32; j++) ss += kx[j] * kx[j];
    for (int off = 32; off; off >>= 1) ss += __shfl_xor(ss, off);
    const float sc = 1.0f / fmaxf(sqrtf(ss), 1e-12f);
    for (int c = 0; c < 4; c++) {
      half8 h = *(const half8*)(Vr + c * 8);
      for (int j = 0; j < 8; j++)
        acc[c * 8 + j] += kx[c * 8 + j] * sc * (float)h[j];
    }
  }
  float* Ap = A + (long)b * DMODEL + d0;
  for (int j = 0; j < 32; j++) atomicAdd(&Ap[j], acc[j]);
}

// ---------------------------------------------------------------- Y1 = A ⊙ rope(Q), in place in Q slice
__global__ __launch_bounds__(256) void k_make_y1(
    _Float16* __restrict__ QKV, const float2* __restrict__ tab,
    const float* __restrict__ A) {
  const long idx = (long)blockIdx.x * 256 + threadIdx.x;
  const long n   = idx >> 8;
  const int  c   = (int)(idx & 255);
  const int  d   = c * 8;
  const int  b   = (int)(n >> 12);
  const int  s   = (int)(n & SMASK);
  _Float16* Qp = QKV + n * E1 + d;
  half8 h = *(half8*)Qp;
  float x[8];
  for (int j = 0; j < 8; j++) x[j] = (float)h[j];
  if (d < ROT) {
    const float2* trow = tab + ((long)s << 9) + (d >> 1);
    for (int p = 0; p < 4; p++) {
      float2 cs2 = trow[p];
      float x0 = x[2 * p], x1 = x[2 * p + 1];
      x[2 * p]     = x0 * cs2.x - x1 * cs2.y;
      x[2 * p + 1] = x1 * cs2.x + x0 * cs2.y;
    }
  }
  const float* Ap = A + (long)b * DMODEL + d;
  for (int j = 0; j < 8; j++) x[j] *= Ap[j];
  half8 o;
  for (int j = 0; j < 8; j++) o[j] = (_Float16)x[j];
  *(half8*)Qp = o;
}

// ---------------------------------------------------------------- launch
extern "C" void kernel_launch(void* const* d_in, const int* in_sizes, int n_in,
                              void* d_out, int out_size, void* d_ws, size_t ws_size,
                              hipStream_t stream) {
  const float* X     = (const float*)d_in[0];  // [8,4096,2048]
  const float* W_in  = (const float*)d_in[1];  // [6144,2048]
  const float* b_in  = (const float*)d_in[2];  // [6144]
  const float* W_out = (const float*)d_in[3];  // [2048,2048]
  const float* b_out = (const float*)d_in[4];  // [2048]
  float* Out = (float*)d_out;

  char* ws = (char*)d_ws;
  _Float16* Xh  = (_Float16*)(ws);                 // 134,217,728 B (dead after GEMM1)
  _Float16* W1h = (_Float16*)(ws + 134217728L);    //  25,165,824 B
  _Float16* W2h = (_Float16*)(ws + 159383552L);    //   8,388,608 B
  _Float16* QKV = (_Float16*)(ws + 167772160L);    // 402,653,184 B
  float*    A   = (float*)  (ws + 570425344L);     //      65,536 B
  float2*   TAB = (float2*)(ws);                   // 16,777,216 B, reuses Xh slot

  k_f2h<<<65536, 256, 0, stream>>>(X,     Xh,  N_TOK * DMODEL);
  k_f2h<<<12288, 256, 0, stream>>>(W_in,  W1h, E1 * DMODEL);
  k_f2h<<< 4096, 256, 0, stream>>>(W_out, W2h, DMODEL * DMODEL);
  k_zero<<<64, 256, 0, stream>>>(A, 8 * (int)DMODEL);

  // GEMM1: QKV[32768][6144] = Xh * W1h^T + b_in   (128 x 24 tiles of 256^2)
  k_gemm256<24, 2048L, 6144L, false><<<3072, 512, 0, stream>>>(
      Xh, W1h, b_in, nullptr, QKV);
  k_tab<<<8192, 256, 0, stream>>>(TAB);            // overwrites Xh (now dead)
  k_reduce_a<<<2048, 256, 0, stream>>>(QKV, TAB, A);
  k_make_y1<<<32768, 256, 0, stream>>>(QKV, TAB, A);
  // GEMM2: Out[32768][2048] = Y1 * W2h^T + b_out + X   (128 x 8 tiles)
  k_gemm256<8, 6144L, 2048L, true><<<1024, 512, 0, stream>>>(
      QKV, W2h, b_out, X, Out);
}

// Round 4
// 1766.869 us; speedup vs baseline: 1.9099x; 1.9099x over previous
//
#include <hip/hip_runtime.h>

// Problem constants: B=8, S=4096, D=2048
#define N_TOK   32768L
#define DMODEL  2048L
#define E1      6144L
#define ROT     1024
#define SMASK   4095

typedef __attribute__((ext_vector_type(8))) _Float16 half8;
typedef __attribute__((ext_vector_type(4))) _Float16 half4;
typedef __attribute__((ext_vector_type(4))) float    floatx4;
typedef __attribute__((ext_vector_type(4))) float    float4v;

// async global->LDS, 16B/lane; LDS dest = wave-uniform base + lane*16.
__device__ inline void gld16(const void* g, void* l) {
  __builtin_amdgcn_global_load_lds(
      (const __attribute__((address_space(1))) unsigned int*)g,
      (__attribute__((address_space(3))) unsigned int*)l,
      16, 0, 0);
}

// ---------------------------------------------------------------- converts
__global__ __launch_bounds__(256) void k_f2h(const float* __restrict__ in,
                                             _Float16* __restrict__ out,
                                             long nElem) {
  long i = ((long)blockIdx.x * 256 + threadIdx.x) * 4;
  if (i + 3 < nElem) {
    float4v v = *(const float4v*)(in + i);
    half4 o;
    o[0] = (_Float16)v[0]; o[1] = (_Float16)v[1];
    o[2] = (_Float16)v[2]; o[3] = (_Float16)v[3];
    *(half4*)(out + i) = o;
  }
}

// ---------------------------------------------------------------- rope table
__global__ __launch_bounds__(256) void k_tab(float2* __restrict__ tab) {
  int i = blockIdx.x * 256 + threadIdx.x;   // [0, 4096*512)
  int s = i >> 9, j = i & 511;
  float invf = (float)pow(10000.0, -(double)j / 512.0);
  float ang  = (float)s * invf;
  double sd, cd; sincos((double)ang, &sd, &cd);
  float2 o; o.x = (float)cd; o.y = (float)sd;
  tab[i] = o;
}

// ---------------------------------------------------------------- GEMM 256x256, 8-phase
// (round-2 measured config: 880 us, MfmaUtil 41.8%, 0 bank conflicts)
// C[m][e] = sum_d A[m][d]*B[e][d] (+bias) (+X residual, fp32 out)
//
// 512 thr = 8 waves (2M x 4N). Per-wave output 128x64: two 64-row A-halves x
// two 32-col B-halves -> 4 quadrants, one per phase, K=64 per phase.
// Quadrant order (0,0)->(0,1)->(1,1)->(1,0): af (A-half frags, 8 reads)
// reused across phase pairs; bf reloaded per phase (B0 re-read at P4).
// Reads/phase = {12,4,8,4} = 28/K-tile.
//
// LDS 128 KiB: As/Bs[buf(2)][half(2)][128 rows][8 chunks of 16B], bank
// swizzle chunk' = chunk ^ (row&7) applied by inverse-permuting the GLOBAL
// source address (global_load_lds writes linearly). Measured 0 conflicts.
//
// Stage cadence: exactly 1 half-tile per phase, vmcnt(6) at P4/P8 only:
//  P1: B0(T+1)->b1  P2: A0(T+2)->b0  P3: B1(T+2)->b0  P4: A1(T+2)->b0 +vm6
//  P5: B0(T+2)->b0  P6: A0(T+3)->b1  P7: B1(T+3)->b1  P8: A1(T+3)->b1 +vm6
// vm6@P4 retires {prev P6,P7,P8, P1} = tile T+1 complete before P5 (3-phase
// lead on the in-flight loads). vm6@P8 retires {P2..P5} = tile T+2 complete
// before next P1. Every stage targets a slot whose last ds_read closed >=1
// barrier earlier. Last iteration peeled, vmcnt(0) at its P4.

#define MM(qm, qn) do { \
  _Pragma("unroll") for (int m4 = 0; m4 < 4; m4++) \
  _Pragma("unroll") for (int n2 = 0; n2 < 2; n2++) { \
    acc[(qm)*4+m4][(qn)*2+n2] = __builtin_amdgcn_mfma_f32_16x16x32_f16( \
        af[m4][0], bf[n2][0], acc[(qm)*4+m4][(qn)*2+n2], 0, 0, 0); \
    acc[(qm)*4+m4][(qn)*2+n2] = __builtin_amdgcn_mfma_f32_16x16x32_f16( \
        af[m4][1], bf[n2][1], acc[(qm)*4+m4][(qn)*2+n2], 0, 0, 0); \
  } } while (0)

#define LD_A(buf, qm) do { \
  const _Float16* pA_ = &As[(buf)*16384 + (qm)*8192 + baseA]; \
  _Pragma("unroll") for (int m4 = 0; m4 < 4; m4++) { \
    af[m4][0] = *(const half8*)(pA_ + m4*1024 + okA0); \
    af[m4][1] = *(const half8*)(pA_ + m4*1024 + okA1); \
  } } while (0)

#define LD_B(buf, qn) do { \
  const _Float16* pB_ = &Bs[(buf)*16384 + (qn)*8192 + baseB]; \
  _Pragma("unroll") for (int n2 = 0; n2 < 2; n2++) { \
    bf[n2][0] = *(const half8*)(pB_ + n2*1024 + okB0); \
    bf[n2][1] = *(const half8*)(pB_ + n2*1024 + okB1); \
  } } while (0)

#define STG_A(buf, h, kt) do { \
  const _Float16* gA_ = gA + (long)(h)*128*LDA + (long)(kt)*64; \
  gld16(gA_,          dA + (buf)*16384 + (h)*8192); \
  gld16(gA_ + 8*LDA,  dA + (buf)*16384 + (h)*8192 + 512); \
  } while (0)

#define STG_B(buf, h, kt) do { \
  const _Float16* gB_ = gB + (long)(h)*128*2048 + (long)(kt)*64; \
  gld16(gB_,          dB + (buf)*16384 + (h)*8192); \
  gld16(gB_ + 8*2048, dB + (buf)*16384 + (h)*8192 + 512); \
  } while (0)

#define VM6  asm volatile("s_waitcnt vmcnt(6)" ::: "memory")
#define VM0  asm volatile("s_waitcnt vmcnt(0)" ::: "memory")
#define LG8  asm volatile("s_waitcnt lgkmcnt(8)" ::: "memory")
#define NOP_ ((void)0)

#define PHASE(LDRD, STG, HINT, MMA_, WV) do { \
  LDRD; STG; HINT; \
  asm volatile("" ::: "memory"); \
  __builtin_amdgcn_s_barrier(); \
  asm volatile("s_waitcnt lgkmcnt(0)" ::: "memory"); \
  __builtin_amdgcn_sched_barrier(0); \
  __builtin_amdgcn_s_setprio(1); \
  MMA_; \
  __builtin_amdgcn_s_setprio(0); \
  WV; \
  asm volatile("" ::: "memory"); \
  __builtin_amdgcn_s_barrier(); \
  asm volatile("" ::: "memory"); \
  } while (0)

template <int EB, long LDA, long LDC, bool FP32OUT>
__global__ __launch_bounds__(512, 2) void k_gemm256(
    const _Float16* __restrict__ Ag, const _Float16* __restrict__ Bg,
    const float* __restrict__ bias, const float* __restrict__ Xres,
    void* __restrict__ Cout) {
  __shared__ _Float16 As[32768];   // 64 KiB
  __shared__ _Float16 Bs[32768];   // 64 KiB

  const int t    = threadIdx.x;
  const int w    = t >> 6;
  const int l    = t & 63;
  const int quad = l >> 4;
  const int ln   = l & 15;
  const int wr   = w >> 2;   // 0..1
  const int wc   = w & 3;    // 0..3

  // XCD-aware bijective remap (nwg%8==0), then e-major (A-panel L2 reuse).
  const int nwg = 128 * EB;
  const int bid = ((int)blockIdx.x & 7) * (nwg >> 3) + ((int)blockIdx.x >> 3);
  const int eb  = bid % EB;
  const int mb  = bid / EB;
  const long mRow0 = (long)mb * 256;
  const long eCol0 = (long)eb * 256;

  // staging per-thread geometry (inverse-swizzled source)
  const int stR = (w << 4) + (l >> 3);
  const int stC = ((l & 7) ^ (l >> 3)) << 3;
  const _Float16* gA = Ag + (mRow0 + stR) * LDA  + stC;
  const _Float16* gB = Bg + (eCol0 + stR) * 2048 + stC;
  _Float16* dA = &As[(w * 128 + l) * 8];
  _Float16* dB = &Bs[(w * 128 + l) * 8];

  // fragment-read geometry
  const int rA = (wr << 6) + ln;          // row within A-half
  const int rB = (wc << 5) + ln;          // row (=col of C) within B-half
  const int baseA = rA * 64;
  const int baseB = rB * 64;
  const int okA0 = ((quad    ) ^ (rA & 7)) << 3;  // kk=0 swizzled chunk
  const int okA1 = ((quad ^ 4) ^ (rA & 7)) << 3;  // kk=1
  const int okB0 = ((quad    ) ^ (rB & 7)) << 3;
  const int okB1 = ((quad ^ 4) ^ (rB & 7)) << 3;

  floatx4 acc[8][4];
#pragma unroll
  for (int i = 0; i < 8; i++)
#pragma unroll
    for (int j = 0; j < 4; j++) acc[i][j] = (floatx4){0.f, 0.f, 0.f, 0.f};
  half8 af[4][2], bf[2][2];

  // prologue: tile0 full (buf0) + A0,B1,A1 of tile1 (buf1). vmcnt(6) retires
  // tile0's 8 loads; tile1's 3 half-tiles stay in flight (P1 stages its B0).
  STG_A(0, 0, 0); STG_B(0, 0, 0); STG_B(0, 1, 0); STG_A(0, 1, 0);
  STG_A(1, 0, 1); STG_B(1, 1, 1); STG_A(1, 1, 1);
  VM6;
  asm volatile("" ::: "memory");
  __builtin_amdgcn_s_barrier();
  asm volatile("" ::: "memory");

#pragma unroll 1
  for (int it = 0; it < 15; ++it) {
    const int T = it * 2;
    PHASE({ LD_A(0,0); LD_B(0,0); }, STG_B(1,0,T+1), LG8,  MM(0,0), NOP_);
    PHASE(LD_B(0,1),                 STG_A(0,0,T+2), NOP_, MM(0,1), NOP_);
    PHASE(LD_A(0,1),                 STG_B(0,1,T+2), NOP_, MM(1,1), NOP_);
    PHASE(LD_B(0,0),                 STG_A(0,1,T+2), NOP_, MM(1,0), VM6);
    PHASE({ LD_A(1,0); LD_B(1,0); }, STG_B(0,0,T+2), LG8,  MM(0,0), NOP_);
    PHASE(LD_B(1,1),                 STG_A(1,0,T+3), NOP_, MM(0,1), NOP_);
    PHASE(LD_A(1,1),                 STG_B(1,1,T+3), NOP_, MM(1,1), NOP_);
    PHASE(LD_B(1,0),                 STG_A(1,1,T+3), NOP_, MM(1,0), VM6);
  }
  // peeled last iteration (T=30): tiles 32/33 don't exist; only tile 31's
  // B0 remains to stage (A0,B1,A1 staged by iter 14). vmcnt(0) at P4.
  PHASE({ LD_A(0,0); LD_B(0,0); }, STG_B(1,0,31), LG8,  MM(0,0), NOP_);
  PHASE(LD_B(0,1),                 NOP_,          NOP_, MM(0,1), NOP_);
  PHASE(LD_A(0,1),                 NOP_,          NOP_, MM(1,1), NOP_);
  PHASE(LD_B(0,0),                 NOP_,          NOP_, MM(1,0), VM0);
  PHASE({ LD_A(1,0); LD_B(1,0); }, NOP_,          LG8,  MM(0,0), NOP_);
  PHASE(LD_B(1,1),                 NOP_,          NOP_, MM(0,1), NOP_);
  PHASE(LD_A(1,1),                 NOP_,          NOP_, MM(1,1), NOP_);
  PHASE(LD_B(1,0),                 NOP_,          NOP_, MM(1,0), NOP_);

  // epilogue. C/D frag: col = lane&15, row = quad*4 + reg.
#pragma unroll
  for (int nt = 0; nt < 4; nt++) {
    const long e = eCol0 + ((nt >> 1) * 128 + (wc << 5) + ((nt & 1) << 4) + ln);
    const float bi = bias[e];
#pragma unroll
    for (int mt = 0; mt < 8; mt++) {
      const long m0 = mRow0 +
          ((mt >> 2) * 128 + (wr << 6) + ((mt & 3) << 4) + (quad << 2));
#pragma unroll
      for (int r = 0; r < 4; r++) {
        const long m = m0 + r;
        if constexpr (FP32OUT) {
          ((float*)Cout)[m * LDC + e] = acc[mt][nt][r] + bi + Xres[m * LDC + e];
        } else {
          ((_Float16*)Cout)[m * LDC + e] = (_Float16)(acc[mt][nt][r] + bi);
        }
      }
    }
  }
}

// ---------------------------------------------------------------- reduce A, stage 1
// Part[g][d] = sum over block g's 16 rows of rope(K)/||rope(K)|| * V.
// NO atomics (round-3 lesson: 16.8M device-scope atomics = 512 MiB HBM
// write-through, 1750 us). Cross-wave reduce in LDS; plain stores.
// 2048 blocks x 256 thr; block g covers rows [g*16, g*16+16), all same b.
__global__ __launch_bounds__(256) void k_reduce_part(
    const _Float16* __restrict__ QKV, const float2* __restrict__ tab,
    float* __restrict__ Part) {
  // red[w][j][lane]: transposed so partial writes are conflict-free
  __shared__ float red[4][32][64];
  const int t  = threadIdx.x;
  const int w  = t >> 6;
  const int l  = t & 63;
  const long row0 = (long)blockIdx.x * 16 + w * 4;  // 4 rows per wave
  const int d0 = l * 32;                  // lane covers 32 contiguous d

  float acc[32];
  for (int j = 0; j < 32; j++) acc[j] = 0.f;

  for (int i = 0; i < 4; i++) {
    const long n = row0 + i;
    const int  s = (int)(n & SMASK);
    const _Float16* Kr = QKV + n * E1 + DMODEL     + d0;
    const _Float16* Vr = QKV + n * E1 + 2 * DMODEL + d0;
    float kx[32];
    for (int c = 0; c < 4; c++) {
      half8 h = *(const half8*)(Kr + c * 8);
      for (int j = 0; j < 8; j++) kx[c * 8 + j] = (float)h[j];
    }
    if (d0 < ROT) {
      const float2* trow = tab + ((long)s << 9) + (d0 >> 1);
      for (int p = 0; p < 16; p++) {
        float2 cs2 = trow[p];
        float x0 = kx[2 * p], x1 = kx[2 * p + 1];
        kx[2 * p]     = x0 * cs2.x - x1 * cs2.y;
        kx[2 * p + 1] = x1 * cs2.x + x0 * cs2.y;
      }
    }
    float ss = 0.f;
    for (int j = 0; j < 32; j++) ss += kx[j] * kx[j];
    for (int off = 32; off; off >>= 1) ss += __shfl_xor(ss, off);
    const float sc = 1.0f / fmaxf(sqrtf(ss), 1e-12f);
    for (int c = 0; c < 4; c++) {
      half8 h = *(const half8*)(Vr + c * 8);
      for (int j = 0; j < 8; j++)
        acc[c * 8 + j] += kx[c * 8 + j] * sc * (float)h[j];
    }
  }
  for (int j = 0; j < 32; j++) red[w][j][l] = acc[j];
  __syncthreads();
  // thread t sums its 8 d-positions across the 4 waves; coalesced stores.
  float out[8];
  for (int j = 0; j < 8; j++) {
    const int d = t * 8 + j;               // d = lsrc*32 + jsrc
    const int lsrc = d >> 5, jsrc = d & 31;
    out[j] = red[0][jsrc][lsrc] + red[1][jsrc][lsrc] +
             red[2][jsrc][lsrc] + red[3][jsrc][lsrc];
  }
  float* Pp = Part + (long)blockIdx.x * 2048 + t * 8;
  *(float4v*)(Pp)     = (float4v){out[0], out[1], out[2], out[3]};
  *(float4v*)(Pp + 4) = (float4v){out[4], out[5], out[6], out[7]};
}

// ---------------------------------------------------------------- reduce A, stage 2
// A[b][d] = sum_{c=0..255} Part[b*256+c][d]. 16 MB coalesced reads.
__global__ __launch_bounds__(256) void k_reduce_final(
    const float* __restrict__ Part, float* __restrict__ A) {
  const int i = blockIdx.x * 256 + threadIdx.x;   // 0..16383
  const int b = i >> 11;
  const int d = i & 2047;
  const float* p = Part + (long)b * 256 * 2048 + d;
  float s = 0.f;
#pragma unroll 8
  for (int c = 0; c < 256; c++) s += p[(long)c * 2048];
  A[i] = s;
}

// ---------------------------------------------------------------- Y1 = A ⊙ rope(Q), in place in Q slice
__global__ __launch_bounds__(256) void k_make_y1(
    _Float16* __restrict__ QKV, const float2* __restrict__ tab,
    const float* __restrict__ A) {
  const long idx = (long)blockIdx.x * 256 + threadIdx.x;
  const long n   = idx >> 8;
  const int  c   = (int)(idx & 255);
  const int  d   = c * 8;
  const int  b   = (int)(n >> 12);
  const int  s   = (int)(n & SMASK);
  _Float16* Qp = QKV + n * E1 + d;
  half8 h = *(half8*)Qp;
  float x[8];
  for (int j = 0; j < 8; j++) x[j] = (float)h[j];
  if (d < ROT) {
    const float2* trow = tab + ((long)s << 9) + (d >> 1);
    for (int p = 0; p < 4; p++) {
      float2 cs2 = trow[p];
      float x0 = x[2 * p], x1 = x[2 * p + 1];
      x[2 * p]     = x0 * cs2.x - x1 * cs2.y;
      x[2 * p + 1] = x1 * cs2.x + x0 * cs2.y;
    }
  }
  const float* Ap = A + (long)b * DMODEL + d;
  for (int j = 0; j < 8; j++) x[j] *= Ap[j];
  half8 o;
  for (int j = 0; j < 8; j++) o[j] = (_Float16)x[j];
  *(half8*)Qp = o;
}

// ---------------------------------------------------------------- launch
extern "C" void kernel_launch(void* const* d_in, const int* in_sizes, int n_in,
                              void* d_out, int out_size, void* d_ws, size_t ws_size,
                              hipStream_t stream) {
  const float* X     = (const float*)d_in[0];  // [8,4096,2048]
  const float* W_in  = (const float*)d_in[1];  // [6144,2048]
  const float* b_in  = (const float*)d_in[2];  // [6144]
  const float* W_out = (const float*)d_in[3];  // [2048,2048]
  const float* b_out = (const float*)d_in[4];  // [2048]
  float* Out = (float*)d_out;

  char* ws = (char*)d_ws;
  _Float16* Xh  = (_Float16*)(ws);                 // 134,217,728 B (dead after GEMM1)
  _Float16* W1h = (_Float16*)(ws + 134217728L);    //  25,165,824 B
  _Float16* W2h = (_Float16*)(ws + 159383552L);    //   8,388,608 B
  _Float16* QKV = (_Float16*)(ws + 167772160L);    // 402,653,184 B
  float*    A   = (float*)  (ws + 570425344L);     //      65,536 B
  float2*   TAB = (float2*)(ws);                   // 16,777,216 B, reuses Xh slot
  float*    PART= (float*)  (ws + 33554432L);      // 16,777,216 B, reuses Xh slot

  k_f2h<<<65536, 256, 0, stream>>>(X,     Xh,  N_TOK * DMODEL);
  k_f2h<<<12288, 256, 0, stream>>>(W_in,  W1h, E1 * DMODEL);
  k_f2h<<< 4096, 256, 0, stream>>>(W_out, W2h, DMODEL * DMODEL);

  // GEMM1: QKV[32768][6144] = Xh * W1h^T + b_in   (128 x 24 tiles of 256^2)
  k_gemm256<24, 2048L, 6144L, false><<<3072, 512, 0, stream>>>(
      Xh, W1h, b_in, nullptr, QKV);
  k_tab<<<8192, 256, 0, stream>>>(TAB);            // overwrites Xh (now dead)
  k_reduce_part<<<2048, 256, 0, stream>>>(QKV, TAB, PART);
  k_reduce_final<<<64, 256, 0, stream>>>(PART, A);
  k_make_y1<<<32768, 256, 0, stream>>>(QKV, TAB, A);
  // GEMM2: Out[32768][2048] = Y1 * W2h^T + b_out + X   (128 x 8 tiles)
  k_gemm256<8, 6144L, 2048L, true><<<1024, 512, 0, stream>>>(
      QKV, W2h, b_out, X, Out);
}

// Round 5
// 1742.659 us; speedup vs baseline: 1.9364x; 1.0139x over previous
//
#include <hip/hip_runtime.h>

// Problem constants: B=8, S=4096, D=2048
#define N_TOK   32768L
#define DMODEL  2048L
#define E1      6144L
#define ROT     1024
#define SMASK   4095

typedef __attribute__((ext_vector_type(8))) _Float16 half8;
typedef __attribute__((ext_vector_type(4))) _Float16 half4;
typedef __attribute__((ext_vector_type(4))) float    floatx4;
typedef __attribute__((ext_vector_type(4))) float    float4v;

// async global->LDS, 16B/lane; LDS dest = wave-uniform base + lane*16.
__device__ inline void gld16(const void* g, void* l) {
  __builtin_amdgcn_global_load_lds(
      (const __attribute__((address_space(1))) unsigned int*)g,
      (__attribute__((address_space(3))) unsigned int*)l,
      16, 0, 0);
}

// ---------------------------------------------------------------- converts
__global__ __launch_bounds__(256) void k_f2h(const float* __restrict__ in,
                                             _Float16* __restrict__ out,
                                             long nElem) {
  long i = ((long)blockIdx.x * 256 + threadIdx.x) * 4;
  if (i + 3 < nElem) {
    float4v v = *(const float4v*)(in + i);
    half4 o;
    o[0] = (_Float16)v[0]; o[1] = (_Float16)v[1];
    o[2] = (_Float16)v[2]; o[3] = (_Float16)v[3];
    *(half4*)(out + i) = o;
  }
}

// ---------------------------------------------------------------- rope table
__global__ __launch_bounds__(256) void k_tab(float2* __restrict__ tab) {
  int i = blockIdx.x * 256 + threadIdx.x;   // [0, 4096*512)
  int s = i >> 9, j = i & 511;
  float invf = (float)pow(10000.0, -(double)j / 512.0);
  float ang  = (float)s * invf;
  double sd, cd; sincos((double)ang, &sd, &cd);
  float2 o; o.x = (float)cd; o.y = (float)sd;
  tab[i] = o;
}

// ---------------------------------------------------------------- GEMM 256x256, 8-phase
// C[m][e] = sum_d A[m][d]*B[e][d] (+bias) (+X residual, fp32 out)
//
// 512 thr = 8 waves (2M x 4N). Per-wave output 128x64: two 64-row A-halves x
// two 32-col B-halves -> 4 quadrants, one per phase, K=64 per phase.
// Quadrant order (0,0)->(0,1)->(1,1)->(1,0). BOTH B-half frag sets stay live
// (bfa=B0, bfb=B1, +16 VGPR) so P4 re-reads nothing: reads/phase =
// {12,4,8,0} = 24/K-tile, and P4/P8 (zero-read) host the vm waits.
//
// ONE barrier per phase (closing only). The old mid-barrier carried no
// correctness load: (a) stage@p targets slots last-read@<=p-1, separated by
// closing barrier of p-1; (b) cross-wave staging readiness = per-wave vm6
// BEFORE the closing barrier, so barrier(P4) certifies all 8 waves' tile-T+1
// loads retired before any wave reads it at P5. Removing it lets waves drift
// within a phase: one wave's ds_reads overlap another's MFMA window (the
// ~450 cyc/phase LDS-read serialization this structure was paying).
//
// LDS 128 KiB: As/Bs[buf(2)][half(2)][128 rows][8 chunks of 16B], bank
// swizzle chunk' = chunk ^ (row&7) applied by inverse-permuting the GLOBAL
// source address (global_load_lds writes linearly). Measured 0 conflicts.
//
// Stage cadence: 1 half-tile per phase, vmcnt(6) at P4/P8 only:
//  P1: B0(T+1)->b1  P2: A0(T+2)->b0  P3: B1(T+2)->b0  P4: A1(T+2)->b0 +vm6
//  P5: B0(T+2)->b0  P6: A0(T+3)->b1  P7: B1(T+3)->b1  P8: A1(T+3)->b1 +vm6
// vm6@P4 retires {prev P6,P7,P8, P1} = tile T+1 complete before P5 (3-phase
// lead). vm6@P8 retires {P2..P5} = tile T+2 complete before next P1.
// Ledger (slot last-read -> overwritten): B0b1@prevP5->P1, A0b0@P1->P2,
// B1b0@P2->P3, A1b0@P3->P4, B0b0@P1->P5, A0b1@P5->P6, B1b1@P6->P7,
// A1b1@P7->P8: all >=1 closing barrier apart. Last iter peeled, vm0 at P4.

#define MM(qm, qn, bfx) do { \
  _Pragma("unroll") for (int m4 = 0; m4 < 4; m4++) \
  _Pragma("unroll") for (int n2 = 0; n2 < 2; n2++) { \
    acc[(qm)*4+m4][(qn)*2+n2] = __builtin_amdgcn_mfma_f32_16x16x32_f16( \
        af[m4][0], bfx[n2][0], acc[(qm)*4+m4][(qn)*2+n2], 0, 0, 0); \
    acc[(qm)*4+m4][(qn)*2+n2] = __builtin_amdgcn_mfma_f32_16x16x32_f16( \
        af[m4][1], bfx[n2][1], acc[(qm)*4+m4][(qn)*2+n2], 0, 0, 0); \
  } } while (0)

#define LD_A(buf, qm) do { \
  const _Float16* pA_ = &As[(buf)*16384 + (qm)*8192 + baseA]; \
  _Pragma("unroll") for (int m4 = 0; m4 < 4; m4++) { \
    af[m4][0] = *(const half8*)(pA_ + m4*1024 + okA0); \
    af[m4][1] = *(const half8*)(pA_ + m4*1024 + okA1); \
  } } while (0)

#define LD_B(buf, qn, dst) do { \
  const _Float16* pB_ = &Bs[(buf)*16384 + (qn)*8192 + baseB]; \
  _Pragma("unroll") for (int n2 = 0; n2 < 2; n2++) { \
    dst[n2][0] = *(const half8*)(pB_ + n2*1024 + okB0); \
    dst[n2][1] = *(const half8*)(pB_ + n2*1024 + okB1); \
  } } while (0)

#define STG_A(buf, h, kt) do { \
  const _Float16* gA_ = gA + (long)(h)*128*LDA + (long)(kt)*64; \
  gld16(gA_,          dA + (buf)*16384 + (h)*8192); \
  gld16(gA_ + 8*LDA,  dA + (buf)*16384 + (h)*8192 + 512); \
  } while (0)

#define STG_B(buf, h, kt) do { \
  const _Float16* gB_ = gB + (long)(h)*128*2048 + (long)(kt)*64; \
  gld16(gB_,          dB + (buf)*16384 + (h)*8192); \
  gld16(gB_ + 8*2048, dB + (buf)*16384 + (h)*8192 + 512); \
  } while (0)

#define VM6  asm volatile("s_waitcnt vmcnt(6)" ::: "memory")
#define VM0  asm volatile("s_waitcnt vmcnt(0)" ::: "memory")
#define LG8  asm volatile("s_waitcnt lgkmcnt(8)" ::: "memory")
#define NOP_ ((void)0)

#define PHASE(LDRD, STG, HINT, MMA_, WV) do { \
  LDRD; STG; HINT; \
  asm volatile("s_waitcnt lgkmcnt(0)" ::: "memory"); \
  __builtin_amdgcn_sched_barrier(0); \
  __builtin_amdgcn_s_setprio(1); \
  MMA_; \
  __builtin_amdgcn_s_setprio(0); \
  WV; \
  asm volatile("" ::: "memory"); \
  __builtin_amdgcn_s_barrier(); \
  asm volatile("" ::: "memory"); \
  } while (0)

template <int EB, long LDA, long LDC, bool FP32OUT>
__global__ __launch_bounds__(512, 2) void k_gemm256(
    const _Float16* __restrict__ Ag, const _Float16* __restrict__ Bg,
    const float* __restrict__ bias, const float* __restrict__ Xres,
    void* __restrict__ Cout) {
  __shared__ _Float16 As[32768];   // 64 KiB
  __shared__ _Float16 Bs[32768];   // 64 KiB

  const int t    = threadIdx.x;
  const int w    = t >> 6;
  const int l    = t & 63;
  const int quad = l >> 4;
  const int ln   = l & 15;
  const int wr   = w >> 2;   // 0..1
  const int wc   = w & 3;    // 0..3

  // XCD-aware bijective remap (nwg%8==0), then e-major (A-panel L2 reuse).
  const int nwg = 128 * EB;
  const int bid = ((int)blockIdx.x & 7) * (nwg >> 3) + ((int)blockIdx.x >> 3);
  const int eb  = bid % EB;
  const int mb  = bid / EB;
  const long mRow0 = (long)mb * 256;
  const long eCol0 = (long)eb * 256;

  // staging per-thread geometry (inverse-swizzled source)
  const int stR = (w << 4) + (l >> 3);
  const int stC = ((l & 7) ^ (l >> 3)) << 3;
  const _Float16* gA = Ag + (mRow0 + stR) * LDA  + stC;
  const _Float16* gB = Bg + (eCol0 + stR) * 2048 + stC;
  _Float16* dA = &As[(w * 128 + l) * 8];
  _Float16* dB = &Bs[(w * 128 + l) * 8];

  // fragment-read geometry
  const int rA = (wr << 6) + ln;          // row within A-half
  const int rB = (wc << 5) + ln;          // row (=col of C) within B-half
  const int baseA = rA * 64;
  const int baseB = rB * 64;
  const int okA0 = ((quad    ) ^ (rA & 7)) << 3;  // kk=0 swizzled chunk
  const int okA1 = ((quad ^ 4) ^ (rA & 7)) << 3;  // kk=1
  const int okB0 = ((quad    ) ^ (rB & 7)) << 3;
  const int okB1 = ((quad ^ 4) ^ (rB & 7)) << 3;

  floatx4 acc[8][4];
#pragma unroll
  for (int i = 0; i < 8; i++)
#pragma unroll
    for (int j = 0; j < 4; j++) acc[i][j] = (floatx4){0.f, 0.f, 0.f, 0.f};
  half8 af[4][2], bfa[2][2], bfb[2][2];

  // prologue: tile0 full (buf0) + A0,B1,A1 of tile1 (buf1). vmcnt(6) retires
  // tile0's 8 loads; tile1's 3 half-tiles stay in flight (P1 stages its B0).
  STG_A(0, 0, 0); STG_B(0, 0, 0); STG_B(0, 1, 0); STG_A(0, 1, 0);
  STG_A(1, 0, 1); STG_B(1, 1, 1); STG_A(1, 1, 1);
  VM6;
  asm volatile("" ::: "memory");
  __builtin_amdgcn_s_barrier();
  asm volatile("" ::: "memory");

#pragma unroll 1
  for (int it = 0; it < 15; ++it) {
    const int T = it * 2;
    PHASE({ LD_A(0,0); LD_B(0,0,bfa); }, STG_B(1,0,T+1), LG8,  MM(0,0,bfa), NOP_);
    PHASE(LD_B(0,1,bfb),                 STG_A(0,0,T+2), NOP_, MM(0,1,bfb), NOP_);
    PHASE(LD_A(0,1),                     STG_B(0,1,T+2), NOP_, MM(1,1,bfb), NOP_);
    PHASE(NOP_,                          STG_A(0,1,T+2), NOP_, MM(1,0,bfa), VM6);
    PHASE({ LD_A(1,0); LD_B(1,0,bfa); }, STG_B(0,0,T+2), LG8,  MM(0,0,bfa), NOP_);
    PHASE(LD_B(1,1,bfb),                 STG_A(1,0,T+3), NOP_, MM(0,1,bfb), NOP_);
    PHASE(LD_A(1,1),                     STG_B(1,1,T+3), NOP_, MM(1,1,bfb), NOP_);
    PHASE(NOP_,                          STG_A(1,1,T+3), NOP_, MM(1,0,bfa), VM6);
  }
  // peeled last iteration (T=30): tiles 32/33 don't exist; only tile 31's
  // B0 remains to stage (A0,B1,A1 staged by iter 14). vmcnt(0) at P4.
  PHASE({ LD_A(0,0); LD_B(0,0,bfa); }, STG_B(1,0,31), LG8,  MM(0,0,bfa), NOP_);
  PHASE(LD_B(0,1,bfb),                 NOP_,          NOP_, MM(0,1,bfb), NOP_);
  PHASE(LD_A(0,1),                     NOP_,          NOP_, MM(1,1,bfb), NOP_);
  PHASE(NOP_,                          NOP_,          NOP_, MM(1,0,bfa), VM0);
  PHASE({ LD_A(1,0); LD_B(1,0,bfa); }, NOP_,          LG8,  MM(0,0,bfa), NOP_);
  PHASE(LD_B(1,1,bfb),                 NOP_,          NOP_, MM(0,1,bfb), NOP_);
  PHASE(LD_A(1,1),                     NOP_,          NOP_, MM(1,1,bfb), NOP_);
  PHASE(NOP_,                          NOP_,          NOP_, MM(1,0,bfa), NOP_);

  // epilogue. C/D frag: col = lane&15, row = quad*4 + reg.
#pragma unroll
  for (int nt = 0; nt < 4; nt++) {
    const long e = eCol0 + ((nt >> 1) * 128 + (wc << 5) + ((nt & 1) << 4) + ln);
    const float bi = bias[e];
#pragma unroll
    for (int mt = 0; mt < 8; mt++) {
      const long m0 = mRow0 +
          ((mt >> 2) * 128 + (wr << 6) + ((mt & 3) << 4) + (quad << 2));
#pragma unroll
      for (int r = 0; r < 4; r++) {
        const long m = m0 + r;
        if constexpr (FP32OUT) {
          ((float*)Cout)[m * LDC + e] = acc[mt][nt][r] + bi + Xres[m * LDC + e];
        } else {
          ((_Float16*)Cout)[m * LDC + e] = (_Float16)(acc[mt][nt][r] + bi);
        }
      }
    }
  }
}

// ---------------------------------------------------------------- reduce A, stage 1
// Part[g][d] = sum over block g's 16 rows of rope(K)/||rope(K)|| * V.
// NO atomics (round-3 lesson: 16.8M device-scope atomics = 512 MiB HBM
// write-through, 1750 us). Cross-wave reduce in LDS; plain stores.
// 2048 blocks x 256 thr; block g covers rows [g*16, g*16+16), all same b.
__global__ __launch_bounds__(256) void k_reduce_part(
    const _Float16* __restrict__ QKV, const float2* __restrict__ tab,
    float* __restrict__ Part) {
  // red[w][j][lane]: transposed so partial writes are conflict-free
  __shared__ float red[4][32][64];
  const int t  = threadIdx.x;
  const int w  = t >> 6;
  const int l  = t & 63;
  const long row0 = (long)blockIdx.x * 16 + w * 4;  // 4 rows per wave
  const int d0 = l * 32;                  // lane covers 32 contiguous d

  float acc[32];
  for (int j = 0; j < 32; j++) acc[j] = 0.f;

  for (int i = 0; i < 4; i++) {
    const long n = row0 + i;
    const int  s = (int)(n & SMASK);
    const _Float16* Kr = QKV + n * E1 + DMODEL     + d0;
    const _Float16* Vr = QKV + n * E1 + 2 * DMODEL + d0;
    float kx[32];
    for (int c = 0; c < 4; c++) {
      half8 h = *(const half8*)(Kr + c * 8);
      for (int j = 0; j < 8; j++) kx[c * 8 + j] = (float)h[j];
    }
    if (d0 < ROT) {
      const float2* trow = tab + ((long)s << 9) + (d0 >> 1);
      for (int p = 0; p < 16; p++) {
        float2 cs2 = trow[p];
        float x0 = kx[2 * p], x1 = kx[2 * p + 1];
        kx[2 * p]     = x0 * cs2.x - x1 * cs2.y;
        kx[2 * p + 1] = x1 * cs2.x + x0 * cs2.y;
      }
    }
    float ss = 0.f;
    for (int j = 0; j < 32; j++) ss += kx[j] * kx[j];
    for (int off = 32; off; off >>= 1) ss += __shfl_xor(ss, off);
    const float sc = 1.0f / fmaxf(sqrtf(ss), 1e-12f);
    for (int c = 0; c < 4; c++) {
      half8 h = *(const half8*)(Vr + c * 8);
      for (int j = 0; j < 8; j++)
        acc[c * 8 + j] += kx[c * 8 + j] * sc * (float)h[j];
    }
  }
  for (int j = 0; j < 32; j++) red[w][j][l] = acc[j];
  __syncthreads();
  // thread t sums its 8 d-positions across the 4 waves; coalesced stores.
  float out[8];
  for (int j = 0; j < 8; j++) {
    const int d = t * 8 + j;               // d = lsrc*32 + jsrc
    const int lsrc = d >> 5, jsrc = d & 31;
    out[j] = red[0][jsrc][lsrc] + red[1][jsrc][lsrc] +
             red[2][jsrc][lsrc] + red[3][jsrc][lsrc];
  }
  float* Pp = Part + (long)blockIdx.x * 2048 + t * 8;
  *(float4v*)(Pp)     = (float4v){out[0], out[1], out[2], out[3]};
  *(float4v*)(Pp + 4) = (float4v){out[4], out[5], out[6], out[7]};
}

// ---------------------------------------------------------------- reduce A, stage 2
// A[b][d] = sum_{c=0..255} Part[b*256+c][d]. 16 MB coalesced reads.
__global__ __launch_bounds__(256) void k_reduce_final(
    const float* __restrict__ Part, float* __restrict__ A) {
  const int i = blockIdx.x * 256 + threadIdx.x;   // 0..16383
  const int b = i >> 11;
  const int d = i & 2047;
  const float* p = Part + (long)b * 256 * 2048 + d;
  float s = 0.f;
#pragma unroll 8
  for (int c = 0; c < 256; c++) s += p[(long)c * 2048];
  A[i] = s;
}

// ---------------------------------------------------------------- Y1 = A ⊙ rope(Q), in place in Q slice
__global__ __launch_bounds__(256) void k_make_y1(
    _Float16* __restrict__ QKV, const float2* __restrict__ tab,
    const float* __restrict__ A) {
  const long idx = (long)blockIdx.x * 256 + threadIdx.x;
  const long n   = idx >> 8;
  const int  c   = (int)(idx & 255);
  const int  d   = c * 8;
  const int  b   = (int)(n >> 12);
  const int  s   = (int)(n & SMASK);
  _Float16* Qp = QKV + n * E1 + d;
  half8 h = *(half8*)Qp;
  float x[8];
  for (int j = 0; j < 8; j++) x[j] = (float)h[j];
  if (d < ROT) {
    const float2* trow = tab + ((long)s << 9) + (d >> 1);
    for (int p = 0; p < 4; p++) {
      float2 cs2 = trow[p];
      float x0 = x[2 * p], x1 = x[2 * p + 1];
      x[2 * p]     = x0 * cs2.x - x1 * cs2.y;
      x[2 * p + 1] = x1 * cs2.x + x0 * cs2.y;
    }
  }
  const float* Ap = A + (long)b * DMODEL + d;
  for (int j = 0; j < 8; j++) x[j] *= Ap[j];
  half8 o;
  for (int j = 0; j < 8; j++) o[j] = (_Float16)x[j];
  *(half8*)Qp = o;
}

// ---------------------------------------------------------------- launch
extern "C" void kernel_launch(void* const* d_in, const int* in_sizes, int n_in,
                              void* d_out, int out_size, void* d_ws, size_t ws_size,
                              hipStream_t stream) {
  const float* X     = (const float*)d_in[0];  // [8,4096,2048]
  const float* W_in  = (const float*)d_in[1];  // [6144,2048]
  const float* b_in  = (const float*)d_in[2];  // [6144]
  const float* W_out = (const float*)d_in[3];  // [2048,2048]
  const float* b_out = (const float*)d_in[4];  // [2048]
  float* Out = (float*)d_out;

  char* ws = (char*)d_ws;
  _Float16* Xh  = (_Float16*)(ws);                 // 134,217,728 B (dead after GEMM1)
  _Float16* W1h = (_Float16*)(ws + 134217728L);    //  25,165,824 B
  _Float16* W2h = (_Float16*)(ws + 159383552L);    //   8,388,608 B
  _Float16* QKV = (_Float16*)(ws + 167772160L);    // 402,653,184 B
  float*    A   = (float*)  (ws + 570425344L);     //      65,536 B
  float2*   TAB = (float2*)(ws);                   // 16,777,216 B, reuses Xh slot
  float*    PART= (float*)  (ws + 33554432L);      // 16,777,216 B, reuses Xh slot

  k_f2h<<<65536, 256, 0, stream>>>(X,     Xh,  N_TOK * DMODEL);
  k_f2h<<<12288, 256, 0, stream>>>(W_in,  W1h, E1 * DMODEL);
  k_f2h<<< 4096, 256, 0, stream>>>(W_out, W2h, DMODEL * DMODEL);

  // GEMM1: QKV[32768][6144] = Xh * W1h^T + b_in   (128 x 24 tiles of 256^2)
  k_gemm256<24, 2048L, 6144L, false><<<3072, 512, 0, stream>>>(
      Xh, W1h, b_in, nullptr, QKV);
  k_tab<<<8192, 256, 0, stream>>>(TAB);            // overwrites Xh (now dead)
  k_reduce_part<<<2048, 256, 0, stream>>>(QKV, TAB, PART);
  k_reduce_final<<<64, 256, 0, stream>>>(PART, A);
  k_make_y1<<<32768, 256, 0, stream>>>(QKV, TAB, A);
  // GEMM2: Out[32768][2048] = Y1 * W2h^T + b_out + X   (128 x 8 tiles)
  k_gemm256<8, 6144L, 2048L, true><<<1024, 512, 0, stream>>>(
      QKV, W2h, b_out, X, Out);
}